// Round 13
// baseline (74.990 us; speedup 1.0000x reference)
//
#include <hip/hip_runtime.h>

#define HH 32
#define WW 32
#define NPOS 512
#define TILE 8            // spatial positions per block (row segment)
#define PPAD 516          // padded p-stride: 516 % 32 == 4
#define NTHR 512          // 8 waves: wave = (bhalf, bpair); lane = oct*8 + hwl
#define NBLK 128          // 32 rows x 4 col-segments
#define NLAYERS 4
#define FSTR 16           // ints per flag slot (64 B line)
#define FLAGV(L) (0x5EED0001 + (L))   // != 0xAAAAAAAA ws-poison -> no memset needed

// Device-coherent (cross-XCD) state access: relaxed agent-scope atomics (sc1).
__device__ __forceinline__ float ld_dev(const float* p) {
    return __hip_atomic_load(p, __ATOMIC_RELAXED, __HIP_MEMORY_SCOPE_AGENT);
}
__device__ __forceinline__ void st_dev(float* p, float v) {
    __hip_atomic_store(p, v, __ATOMIC_RELAXED, __HIP_MEMORY_SCOPE_AGENT);
}
__device__ __forceinline__ float sigm(float g) {
    return __builtin_amdgcn_rcpf(1.0f + __expf(-g));
}

__device__ __forceinline__ void make_v(const float c[9], float* v) {
    // v[lo] over window elems m=4..8 (MSB-first)
    float a2[2], a4[4], a8[8], a16[16];
    a2[0] = 1.0f - c[4]; a2[1] = c[4];
    #pragma unroll
    for (int i = 0; i < 2; ++i)  { a4[2*i]  = a2[i]  * (1.0f - c[5]); a4[2*i+1]  = a2[i]  * c[5]; }
    #pragma unroll
    for (int i = 0; i < 4; ++i)  { a8[2*i]  = a4[i]  * (1.0f - c[6]); a8[2*i+1]  = a4[i]  * c[6]; }
    #pragma unroll
    for (int i = 0; i < 8; ++i)  { a16[2*i] = a8[i]  * (1.0f - c[7]); a16[2*i+1] = a8[i]  * c[7]; }
    #pragma unroll
    for (int i = 0; i < 16; ++i) { v[2*i]   = a16[i] * (1.0f - c[8]); v[2*i+1]   = a16[i] * c[8]; }
}

__global__ __launch_bounds__(NTHR) void asic_fused(
    const float* __restrict__ x,     // (16,32,32)
    const float* __restrict__ tg,    // (4,512,32,32)
    float* __restrict__ bufA,        // layer-0 state
    float* __restrict__ bufB,        // layer-1 state
    float* __restrict__ bufC,        // layer-2 state
    float* __restrict__ out,         // layer-3 state
    int* __restrict__ flags)         // 3*8*128 per-wave flag slots (poisoned, no memset)
{
    __shared__ float lut[NLAYERS][TILE * PPAD];  // 66 KB

    const int t   = threadIdx.x;          // 0..511
    const int bid = blockIdx.x;
    // XCD swizzle (r12-validated): segs of one row -> same XCD -> gate-line dedup
    const int h   = bid & 31;
    const int seg = bid >> 5;
    const int w0  = seg * TILE;
    const int hw0 = h * 32 + w0;
    const int tid = (h << 2) | seg;       // un-swizzled tile id for the flag lattice

    // wave-local decomposition: all 8 hi-octants of a cell live in ONE wave
    const int lane = t & 63;
    const int wv   = t >> 6;              // 0..7 = (bhalf<<2)|bpair
    const int hwl  = lane & 7;
    const int oct  = lane >> 3;           // hi = 2*oct, 2*oct+1
    const int bh   = wv >> 2;
    const int bp   = wv & 3;
    const int b0   = bh * 8 + 2 * bp;
    const int w    = w0 + hwl;
    const int bit0 = (oct >> 2) & 1, bit1 = (oct >> 1) & 1, bit2 = oct & 1;

    // ---- stage ALL 4 layer LUTs (8 float4 iters/thread, r12 pattern)
    #pragma unroll
    for (int k = 0; k < 8; ++k) {
        int f     = t + NTHR * k;         // 0..4095
        int layer = f >> 10;
        int r     = f & 1023;
        int p     = r >> 1;
        int half  = r & 1;
        float4 g4 = *(const float4*)(tg + (size_t)layer * NPOS * HH * WW + p * (HH * WW) + hw0 + half * 4);
        int pb = half * 4;
        lut[layer][(pb + 0) * PPAD + p] = sigm(g4.x);
        lut[layer][(pb + 1) * PPAD + p] = sigm(g4.y);
        lut[layer][(pb + 2) * PPAD + p] = sigm(g4.z);
        lut[layer][(pb + 3) * PPAD + p] = sigm(g4.w);
    }

    // ---- gather layer-0 windows from x (plain loads; overlap with staging)
    float c0[9], c1[9];
    {
        const float* s0 = x + b0 * (HH * WW);
        const float* s1 = s0 + (HH * WW);
        #pragma unroll
        for (int i = 0; i < 3; ++i) {
            int row = ((h + i) & 31) * 32;
            #pragma unroll
            for (int j = 0; j < 3; ++j) {
                int idx = row + ((w + j - 1 + 32) & 31);
                c0[3 * i + j] = s0[idx];
                c1[3 * i + j] = s1[idx];
            }
        }
    }

    __syncthreads();   // LUTs ready — the ONLY block-wide barrier

    float* dsts[NLAYERS] = {bufA, bufB, bufC, out};

    for (int layer = 0; layer < NLAYERS; ++layer) {
        float* dst = dsts[layer];

        if (layer > 0) {
            // wave-local sync: wait for the 9 same-(bh,bp) producer waves of layer-1.
            // Own tile is in the 3x3 -> this also orders against our own stores.
            if (lane < 9) {
                int dr = lane / 3, ds = lane % 3 - 1;
                int pid = (((h + dr) & 31) << 2) | ((seg + ds) & 3);
                const int* f = &flags[(((layer - 1) * 8 + wv) * NBLK + pid) * FSTR];
                while (__hip_atomic_load(f, __ATOMIC_RELAXED, __HIP_MEMORY_SCOPE_AGENT) != FLAGV(layer - 1)) {
                    __builtin_amdgcn_s_sleep(2);
                }
            }
            __atomic_signal_fence(__ATOMIC_ACQUIRE);
            const float* s0 = dsts[layer - 1] + b0 * (HH * WW);
            const float* s1 = s0 + (HH * WW);
            #pragma unroll
            for (int i = 0; i < 3; ++i) {
                int row = ((h + i) & 31) * 32;
                #pragma unroll
                for (int j = 0; j < 3; ++j) {
                    int idx = row + ((w + j - 1 + 32) & 31);
                    c0[3 * i + j] = ld_dev(s0 + idx);
                    c1[3 * i + j] = ld_dev(s1 + idx);
                }
            }
        }

        float v0[32], v1[32];
        make_v(c0, v0);
        make_v(c1, v1);

        float base0 = (bit0 ? c0[0] : 1.0f - c0[0]) * (bit1 ? c0[1] : 1.0f - c0[1]) * (bit2 ? c0[2] : 1.0f - c0[2]);
        float base1 = (bit0 ? c1[0] : 1.0f - c1[0]) * (bit1 ? c1[1] : 1.0f - c1[1]) * (bit2 ? c1[2] : 1.0f - c1[2]);
        float uA0 = base0 * (1.0f - c0[3]), uB0 = base0 * c0[3];
        float uA1 = base1 * (1.0f - c1[3]), uB1 = base1 * c1[3];

        // ---- dot: 16 b128 LDS reads (distinct per lane: 2-way conflict = free)
        const float4* lutp = (const float4*)(&lut[layer][0] + hwl * PPAD);
        const float4* A = lutp + (2 * oct) * 8;
        const float4* B = A + 8;
        float sA0 = 0.f, sA1 = 0.f, sB0 = 0.f, sB1 = 0.f;
        #pragma unroll
        for (int l4 = 0; l4 < 8; ++l4) {
            float4 LA = A[l4];
            float4 LB = B[l4];
            sA0 = fmaf(LA.x, v0[4*l4+0], sA0); sA0 = fmaf(LA.y, v0[4*l4+1], sA0);
            sA0 = fmaf(LA.z, v0[4*l4+2], sA0); sA0 = fmaf(LA.w, v0[4*l4+3], sA0);
            sA1 = fmaf(LA.x, v1[4*l4+0], sA1); sA1 = fmaf(LA.y, v1[4*l4+1], sA1);
            sA1 = fmaf(LA.z, v1[4*l4+2], sA1); sA1 = fmaf(LA.w, v1[4*l4+3], sA1);
            sB0 = fmaf(LB.x, v0[4*l4+0], sB0); sB0 = fmaf(LB.y, v0[4*l4+1], sB0);
            sB0 = fmaf(LB.z, v0[4*l4+2], sB0); sB0 = fmaf(LB.w, v0[4*l4+3], sB0);
            sB1 = fmaf(LB.x, v1[4*l4+0], sB1); sB1 = fmaf(LB.y, v1[4*l4+1], sB1);
            sB1 = fmaf(LB.z, v1[4*l4+2], sB1); sB1 = fmaf(LB.w, v1[4*l4+3], sB1);
        }
        float acc0 = fmaf(uA0, sA0, uB0 * sB0);
        float acc1 = fmaf(uA1, sA1, uB1 * sB1);

        // ---- in-wave reduction over oct (lane bits 3..5): no LDS, no barrier
        #pragma unroll
        for (int m = 8; m <= 32; m <<= 1) {
            acc0 += __shfl_xor(acc0, m, 64);
            acc1 += __shfl_xor(acc1, m, 64);
        }

        if (oct == 0) {   // 8 lanes store this wave's 16 cells (2 contiguous rows of 8)
            float r0 = fminf(fmaxf(acc0, 0.0f), 1.0f);
            float r1 = fminf(fmaxf(acc1, 0.0f), 1.0f);
            st_dev(dst + (size_t)b0 * (HH * WW) + h * 32 + w0 + hwl, r0);
            st_dev(dst + (size_t)(b0 + 1) * (HH * WW) + h * 32 + w0 + hwl, r1);
        }

        if (layer < NLAYERS - 1) {
            // drain this wave's state stores (acked at coherence point), then publish
            __atomic_signal_fence(__ATOMIC_RELEASE);
            __builtin_amdgcn_s_waitcnt(0);
            __atomic_signal_fence(__ATOMIC_RELEASE);
            if (lane == 0) {
                __hip_atomic_store(&flags[((layer * 8 + wv) * NBLK + tid) * FSTR], FLAGV(layer),
                                   __ATOMIC_RELAXED, __HIP_MEMORY_SCOPE_AGENT);
            }
        }
    }
}

extern "C" void kernel_launch(void* const* d_in, const int* in_sizes, int n_in,
                              void* d_out, int out_size, void* d_ws, size_t ws_size,
                              hipStream_t stream) {
    const float* x  = (const float*)d_in[0];   // (16,32,32)
    const float* tg = (const float*)d_in[1];   // (4,512,32,32)
    float* out  = (float*)d_out;
    float* bufA = (float*)d_ws;                          // 64 KB
    float* bufB = bufA + 16 * HH * WW;                   // 64 KB
    float* bufC = bufB + 16 * HH * WW;                   // 64 KB
    int*   flags = (int*)((char*)d_ws + 256 * 1024);     // 3*8*128 slots x 64 B = 192 KB

    // no memset: flags are poison-valued 0xAAAAAAAA; producers store FLAGV(layer)
    asic_fused<<<NBLK, NTHR, 0, stream>>>(x, tg, bufA, bufB, bufC, out, flags);
}

// Round 14
// 73.094 us; speedup vs baseline: 1.0259x; 1.0259x over previous
//
#include <hip/hip_runtime.h>

#define HH 32
#define WW 32
#define NPOS 512
#define TILE 8            // spatial positions per block (row segment)
#define PPAD 516          // padded p-stride: 516 % 32 == 4 -> conflict-free float4 dot reads
#define NTHR 512          // two 256-thread batch-half groups sharing one LUT
#define NBLK 128          // 32 rows x 4 col-segments
#define NLAYERS 4
#define RPAD 33           // float2 stride per oct in reduction buffer
#define FSTR 16           // ints per flag slot (64 B) -> one cache line per flag
#define FLAGV(L) (0x5EED0001 + (L))   // != 0xAAAAAAAA ws-poison -> no memset needed

// Device-coherent (cross-XCD) state access: relaxed agent-scope atomics (sc1).
__device__ __forceinline__ float ld_dev(const float* p) {
    return __hip_atomic_load(p, __ATOMIC_RELAXED, __HIP_MEMORY_SCOPE_AGENT);
}
__device__ __forceinline__ void st_dev(float* p, float v) {
    __hip_atomic_store(p, v, __ATOMIC_RELAXED, __HIP_MEMORY_SCOPE_AGENT);
}
__device__ __forceinline__ float sigm(float g) {
    return __builtin_amdgcn_rcpf(1.0f + __expf(-g));
}

__device__ __forceinline__ void make_v(const float c[9], float* v) {
    // v[lo] over window elems m=4..8 (MSB-first)
    float a2[2], a4[4], a8[8], a16[16];
    a2[0] = 1.0f - c[4]; a2[1] = c[4];
    #pragma unroll
    for (int i = 0; i < 2; ++i)  { a4[2*i]  = a2[i]  * (1.0f - c[5]); a4[2*i+1]  = a2[i]  * c[5]; }
    #pragma unroll
    for (int i = 0; i < 4; ++i)  { a8[2*i]  = a4[i]  * (1.0f - c[6]); a8[2*i+1]  = a4[i]  * c[6]; }
    #pragma unroll
    for (int i = 0; i < 8; ++i)  { a16[2*i] = a8[i]  * (1.0f - c[7]); a16[2*i+1] = a8[i]  * c[7]; }
    #pragma unroll
    for (int i = 0; i < 16; ++i) { v[2*i]   = a16[i] * (1.0f - c[8]); v[2*i+1]   = a16[i] * c[8]; }
}

__global__ __launch_bounds__(NTHR) void asic_fused(
    const float* __restrict__ x,     // (16,32,32)
    const float* __restrict__ tg,    // (4,512,32,32)
    float* __restrict__ bufA,        // layer-0 state
    float* __restrict__ bufB,        // layer-1 state
    float* __restrict__ bufC,        // layer-2 state (own buffer: WAR-safe under skew)
    float* __restrict__ out,         // layer-3 state
    int* __restrict__ flags)         // 3*2*128 per-half flag slots (poisoned, no memset)
{
    __shared__ float  lut[NLAYERS][TILE * PPAD];  // 66 KB: all layers
    __shared__ float2 red[2][8 * RPAD];           // 4.2 KB

    const int t   = threadIdx.x;          // 0..511
    const int bid = blockIdx.x;
    // XCD swizzle (r12-validated): segs of one row -> same XCD -> gate-line dedup
    const int h   = bid & 31;             // tile row 0..31
    const int seg = bid >> 5;             // col segment 0..3
    const int w0  = seg * TILE;
    const int hw0 = h * 32 + w0;
    const int tid = (h << 2) | seg;       // tile id on the flag lattice

    // ---- per-half compute layout (r6..r12-validated)
    const int th    = t & 255;
    const int bhalf = t >> 8;
    const int lane  = t & 63;
    const int hwl   = th & 7;
    const int bp    = (th >> 3) & 3;
    const int oct   = th >> 5;            // hi = 2*oct, 2*oct+1
    const int w     = w0 + hwl;
    const int b0    = bhalf * 8 + 2 * bp;
    const int bit0 = (oct >> 2) & 1, bit1 = (oct >> 1) & 1, bit2 = oct & 1;

    // ---- stage layer-0 LUT (float4 loads: 2 iters)
    #pragma unroll
    for (int k = 0; k < 2; ++k) {
        int f    = t + NTHR * k;          // 0..1023
        int p    = f >> 1;
        int half = f & 1;
        float4 g4 = *(const float4*)(tg + p * (HH * WW) + hw0 + half * 4);
        int pb = half * 4;
        lut[0][(pb + 0) * PPAD + p] = sigm(g4.x);
        lut[0][(pb + 1) * PPAD + p] = sigm(g4.y);
        lut[0][(pb + 2) * PPAD + p] = sigm(g4.z);
        lut[0][(pb + 3) * PPAD + p] = sigm(g4.w);
    }

    // ---- gather layer-0 windows from x (plain loads: input, coherent at dispatch)
    float c0[9], c1[9];
    {
        const float* s0 = x + b0 * (HH * WW);
        const float* s1 = s0 + (HH * WW);
        #pragma unroll
        for (int i = 0; i < 3; ++i) {
            int row = ((h + i) & 31) * 32;
            #pragma unroll
            for (int j = 0; j < 3; ++j) {
                int idx = row + ((w + j - 1 + 32) & 31);
                c0[3 * i + j] = s0[idx];
                c1[3 * i + j] = s1[idx];
            }
        }
    }

    __syncthreads();   // lut[0] ready

    // ---- stage layers 1..3 (6 float4 iters): overlaps layer-0 compute below.
    //      LDS-ordering vs layer-1 reads is provided by layer-0's red barrier.
    #pragma unroll
    for (int k = 0; k < 6; ++k) {
        int f     = t + NTHR * k;         // 0..3071
        int layer = 1 + (f >> 10);
        int r     = f & 1023;
        int p     = r >> 1;
        int half  = r & 1;
        float4 g4 = *(const float4*)(tg + (size_t)layer * NPOS * HH * WW + p * (HH * WW) + hw0 + half * 4);
        int pb = half * 4;
        lut[layer][(pb + 0) * PPAD + p] = sigm(g4.x);
        lut[layer][(pb + 1) * PPAD + p] = sigm(g4.y);
        lut[layer][(pb + 2) * PPAD + p] = sigm(g4.z);
        lut[layer][(pb + 3) * PPAD + p] = sigm(g4.w);
    }

    float* dsts[NLAYERS] = {bufA, bufB, bufC, out};

    for (int layer = 0; layer < NLAYERS; ++layer) {
        float* dst = dsts[layer];

        if (layer > 0) {
            // per-half neighbor sync: 9 lanes poll the 9 producer tiles' flags
            // for THIS half. Own tile is in the 3x3 -> orders own reducer's
            // stores (and its red[] reads) before we overwrite/gather.
            if (lane < 9) {
                int dr = lane / 3, ds = lane % 3 - 1;
                int pid = (((h + dr) & 31) << 2) | ((seg + ds) & 3);
                const int* f = &flags[(((layer - 1) * 2 + bhalf) * NBLK + pid) * FSTR];
                while (__hip_atomic_load(f, __ATOMIC_RELAXED, __HIP_MEMORY_SCOPE_AGENT) != FLAGV(layer - 1)) {
                    __builtin_amdgcn_s_sleep(2);
                }
            }
            const float* s0 = dsts[layer - 1] + b0 * (HH * WW);
            const float* s1 = s0 + (HH * WW);
            #pragma unroll
            for (int i = 0; i < 3; ++i) {
                int row = ((h + i) & 31) * 32;
                #pragma unroll
                for (int j = 0; j < 3; ++j) {
                    int idx = row + ((w + j - 1 + 32) & 31);
                    c0[3 * i + j] = ld_dev(s0 + idx);
                    c1[3 * i + j] = ld_dev(s1 + idx);
                }
            }
        }

        float v0[32], v1[32];
        make_v(c0, v0);
        make_v(c1, v1);

        float base0 = (bit0 ? c0[0] : 1.0f - c0[0]) * (bit1 ? c0[1] : 1.0f - c0[1]) * (bit2 ? c0[2] : 1.0f - c0[2]);
        float base1 = (bit0 ? c1[0] : 1.0f - c1[0]) * (bit1 ? c1[1] : 1.0f - c1[1]) * (bit2 ? c1[2] : 1.0f - c1[2]);
        float uA0 = base0 * (1.0f - c0[3]), uB0 = base0 * c0[3];
        float uA1 = base1 * (1.0f - c1[3]), uB1 = base1 * c1[3];

        // ---- dot: 16 b128 LDS reads (4-way broadcast within wave), both batches
        const float4* lutp = (const float4*)(&lut[layer][0] + hwl * PPAD);
        const float4* A = lutp + (2 * oct) * 8;
        const float4* B = A + 8;
        float sA0 = 0.f, sA1 = 0.f, sB0 = 0.f, sB1 = 0.f;
        #pragma unroll
        for (int l4 = 0; l4 < 8; ++l4) {
            float4 LA = A[l4];
            float4 LB = B[l4];
            sA0 = fmaf(LA.x, v0[4*l4+0], sA0); sA0 = fmaf(LA.y, v0[4*l4+1], sA0);
            sA0 = fmaf(LA.z, v0[4*l4+2], sA0); sA0 = fmaf(LA.w, v0[4*l4+3], sA0);
            sA1 = fmaf(LA.x, v1[4*l4+0], sA1); sA1 = fmaf(LA.y, v1[4*l4+1], sA1);
            sA1 = fmaf(LA.z, v1[4*l4+2], sA1); sA1 = fmaf(LA.w, v1[4*l4+3], sA1);
            sB0 = fmaf(LB.x, v0[4*l4+0], sB0); sB0 = fmaf(LB.y, v0[4*l4+1], sB0);
            sB0 = fmaf(LB.z, v0[4*l4+2], sB0); sB0 = fmaf(LB.w, v0[4*l4+3], sB0);
            sB1 = fmaf(LB.x, v1[4*l4+0], sB1); sB1 = fmaf(LB.y, v1[4*l4+1], sB1);
            sB1 = fmaf(LB.z, v1[4*l4+2], sB1); sB1 = fmaf(LB.w, v1[4*l4+3], sB1);
        }
        float acc0 = fmaf(uA0, sA0, uB0 * sB0);
        float acc1 = fmaf(uA1, sA1, uB1 * sB1);

        red[bhalf][oct * RPAD + bp * 8 + hwl] = make_float2(acc0, acc1);
        __syncthreads();   // the ONLY block barrier per layer

        // th<64 is exactly wave 0 (half 0) / wave 4 (half 1): the reducing wave.
        // It stores its half's 64 cells, drains ITS OWN vmcnt (all 64 stores are
        // in this wave), and publishes the per-half flag — no block barrier.
        if (th < 64) {
            int hw  = th & 7;
            int bl  = th >> 3;
            int bpi = bl >> 1, par = bl & 1;
            float s = 0.0f;
            #pragma unroll
            for (int o = 0; o < 8; ++o) {
                float2 r = red[bhalf][o * RPAD + bpi * 8 + hw];
                s += par ? r.y : r.x;
            }
            s = fminf(fmaxf(s, 0.0f), 1.0f);
            st_dev(dst + (size_t)(bhalf * 8 + bl) * (HH * WW) + h * 32 + w0 + hw, s);

            if (layer < NLAYERS - 1) {
                __builtin_amdgcn_s_waitcnt(0);   // stores acked at coherence point
                if (th == 0) {
                    __hip_atomic_store(&flags[((layer * 2 + bhalf) * NBLK + tid) * FSTR],
                                       FLAGV(layer), __ATOMIC_RELAXED, __HIP_MEMORY_SCOPE_AGENT);
                }
            }
        }
    }
}

extern "C" void kernel_launch(void* const* d_in, const int* in_sizes, int n_in,
                              void* d_out, int out_size, void* d_ws, size_t ws_size,
                              hipStream_t stream) {
    const float* x  = (const float*)d_in[0];   // (16,32,32)
    const float* tg = (const float*)d_in[1];   // (4,512,32,32)
    float* out  = (float*)d_out;
    float* bufA = (float*)d_ws;                          // 64 KB
    float* bufB = bufA + 16 * HH * WW;                   // 64 KB
    float* bufC = bufB + 16 * HH * WW;                   // 64 KB
    int*   flags = (int*)((char*)d_ws + 256 * 1024);     // 3*2*128 slots x 64 B = 48 KB

    // no memset: flags are poison-valued 0xAAAAAAAA; producers store FLAGV(layer)
    asic_fused<<<NBLK, NTHR, 0, stream>>>(x, tg, bufA, bufB, bufC, out, flags);
}

// Round 15
// 70.836 us; speedup vs baseline: 1.0586x; 1.0319x over previous
//
#include <hip/hip_runtime.h>

#define HH 32
#define WW 32
#define NPOS 512
#define TILE 8            // spatial positions per block (row segment)
#define PPAD 516          // padded p-stride: 516 % 32 == 4 -> conflict-free float4 dot reads
#define NTHR 512          // two 256-thread batch-half groups sharing one LUT
#define NBLK 128          // 32 rows x 4 col-segments; co-residency proven (r2/r4/r9/r10/r11)
#define NLAYERS 4
#define RPAD 33           // float2 stride per oct in reduction buffer
#define FSTR 16           // ints per flag slot (64 B) -> one cache line per flag
#define FLAGV(L) (0x5EED0001 + (L))   // != 0xAAAAAAAA ws-poison -> no memset needed

// Device-coherent (cross-XCD) state access: relaxed agent-scope atomics (sc1,
// serviced at the shared coherence point; no L1/L2 staleness possible).
__device__ __forceinline__ float ld_dev(const float* p) {
    return __hip_atomic_load(p, __ATOMIC_RELAXED, __HIP_MEMORY_SCOPE_AGENT);
}
__device__ __forceinline__ void st_dev(float* p, float v) {
    __hip_atomic_store(p, v, __ATOMIC_RELAXED, __HIP_MEMORY_SCOPE_AGENT);
}

// Neighbor-local sync (r10/r11/r12-validated): producer flag = sc1 STORE of a
// layer-unique magic (poison can't match -> no memset). __syncthreads drains
// vmcnt before s_barrier, so sc1 state stores are acked before publishing.
// ONE wave polls; the closing barrier broadcasts the release (r13/r14 showed
// per-wave/per-half polling multiplies coherence-point traffic and regresses).
__device__ __forceinline__ void neighbor_sync(int* flags, int layer, int h, int seg) {
    __syncthreads();                       // drain: state stores acked
    const int t = threadIdx.x;
    if (t == 0) {
        __hip_atomic_store(&flags[(layer * NBLK + (h * 4 + seg)) * FSTR], FLAGV(layer),
                           __ATOMIC_RELAXED, __HIP_MEMORY_SCOPE_AGENT);
    }
    if (t < 9) {                           // poll the 9 producer tiles
        int dr = t / 3, ds = t % 3 - 1;    // rows h..h+2, segs seg-1..seg+1
        int pid = (((h + dr) & 31) << 2) | ((seg + ds) & 3);
        const int* f = &flags[(layer * NBLK + pid) * FSTR];
        while (__hip_atomic_load(f, __ATOMIC_RELAXED, __HIP_MEMORY_SCOPE_AGENT) != FLAGV(layer)) {
            __builtin_amdgcn_s_sleep(2);
        }
    }
    __syncthreads();
}

__device__ __forceinline__ void make_v(const float c[9], float* v) {
    // v[lo] over window elems m=4..8 (MSB-first)
    float a2[2], a4[4], a8[8], a16[16];
    a2[0] = 1.0f - c[4]; a2[1] = c[4];
    #pragma unroll
    for (int i = 0; i < 2; ++i)  { a4[2*i]  = a2[i]  * (1.0f - c[5]); a4[2*i+1]  = a2[i]  * c[5]; }
    #pragma unroll
    for (int i = 0; i < 4; ++i)  { a8[2*i]  = a4[i]  * (1.0f - c[6]); a8[2*i+1]  = a4[i]  * c[6]; }
    #pragma unroll
    for (int i = 0; i < 8; ++i)  { a16[2*i] = a8[i]  * (1.0f - c[7]); a16[2*i+1] = a8[i]  * c[7]; }
    #pragma unroll
    for (int i = 0; i < 16; ++i) { v[2*i]   = a16[i] * (1.0f - c[8]); v[2*i+1]   = a16[i] * c[8]; }
}

__device__ __forceinline__ float sigm(float g) {
    return __builtin_amdgcn_rcpf(1.0f + __expf(-g));
}

__global__ __launch_bounds__(NTHR) void asic_fused(
    const float* __restrict__ x,     // (16,32,32)
    const float* __restrict__ tg,    // (4,512,32,32)
    float* __restrict__ bufA,        // layer-0 state
    float* __restrict__ bufB,        // layer-1 state
    float* __restrict__ bufC,        // layer-2 state (own buffer: WAR-safe under skew)
    float* __restrict__ out,         // layer-3 state
    int* __restrict__ flags)         // 3*128 flag slots (poisoned 0xAA, no memset)
{
    __shared__ float  lut[NLAYERS][TILE * PPAD];  // 66 KB: all layers
    __shared__ float2 red[2][8 * RPAD];           // 4.2 KB

    const int t   = threadIdx.x;          // 0..511
    const int bid = blockIdx.x;
    // XCD swizzle: segs of one row -> bids {r, r+32, r+64, r+96}, all == r mod 8
    // -> same XCD L2 -> the shared 128-B gate lines are fetched once, not 4x.
    const int h   = bid & 31;             // tile row 0..31
    const int seg = bid >> 5;             // col segment 0..3
    const int w0  = seg * TILE;
    const int hw0 = h * 32 + w0;

    // ---- per-half compute layout (r6/r9/r10/r11-validated)
    const int th    = t & 255;
    const int bhalf = t >> 8;
    const int hwl   = th & 7;
    const int bp    = (th >> 3) & 3;
    const int oct   = th >> 5;            // hi = 2*oct, 2*oct+1
    const int w     = w0 + hwl;
    const int b0    = bhalf * 8 + 2 * bp;
    const int bit0 = (oct >> 2) & 1, bit1 = (oct >> 1) & 1, bit2 = oct & 1;

    // ---- stage layer-0 LUT (float4 loads: 2 iters, 4x bytes in flight)
    #pragma unroll
    for (int k = 0; k < 2; ++k) {
        int f    = t + NTHR * k;          // 0..1023
        int p    = f >> 1;
        int half = f & 1;                 // positions 4*half .. 4*half+3
        float4 g4 = *(const float4*)(tg + p * (HH * WW) + hw0 + half * 4);
        int pb = half * 4;
        lut[0][(pb + 0) * PPAD + p] = sigm(g4.x);
        lut[0][(pb + 1) * PPAD + p] = sigm(g4.y);
        lut[0][(pb + 2) * PPAD + p] = sigm(g4.z);
        lut[0][(pb + 3) * PPAD + p] = sigm(g4.w);
    }

    // ---- gather layer-0 windows from x (plain loads: input, coherent at dispatch)
    float c0[9], c1[9];
    {
        const float* s0 = x + b0 * (HH * WW);
        const float* s1 = s0 + (HH * WW);
        #pragma unroll
        for (int i = 0; i < 3; ++i) {
            int row = ((h + i) & 31) * 32;
            #pragma unroll
            for (int j = 0; j < 3; ++j) {
                int idx = row + ((w + j - 1 + 32) & 31);
                c0[3 * i + j] = s0[idx];
                c1[3 * i + j] = s1[idx];
            }
        }
    }

    __syncthreads();   // lut[0] ready

    // ---- stage layers 1..3 (6 float4 iters): independent of layer-0 compute;
    //      compiler interleaves these loads/sigmoids with the dot + first sync.
    #pragma unroll
    for (int k = 0; k < 6; ++k) {
        int f     = t + NTHR * k;         // 0..3071
        int layer = 1 + (f >> 10);
        int r     = f & 1023;
        int p     = r >> 1;
        int half  = r & 1;
        float4 g4 = *(const float4*)(tg + (size_t)layer * NPOS * HH * WW + p * (HH * WW) + hw0 + half * 4);
        int pb = half * 4;
        lut[layer][(pb + 0) * PPAD + p] = sigm(g4.x);
        lut[layer][(pb + 1) * PPAD + p] = sigm(g4.y);
        lut[layer][(pb + 2) * PPAD + p] = sigm(g4.z);
        lut[layer][(pb + 3) * PPAD + p] = sigm(g4.w);
    }

    float* dsts[NLAYERS] = {bufA, bufB, bufC, out};
    const float* src = x;

    for (int layer = 0; layer < NLAYERS; ++layer) {
        float* dst = dsts[layer];

        if (layer > 0) {   // gather via sc1 (cross-XCD coherent); layer 0 pre-gathered
            const float* s0 = src + b0 * (HH * WW);
            const float* s1 = s0 + (HH * WW);
            #pragma unroll
            for (int i = 0; i < 3; ++i) {
                int row = ((h + i) & 31) * 32;
                #pragma unroll
                for (int j = 0; j < 3; ++j) {
                    int idx = row + ((w + j - 1 + 32) & 31);
                    c0[3 * i + j] = ld_dev(s0 + idx);
                    c1[3 * i + j] = ld_dev(s1 + idx);
                }
            }
        }

        float v0[32], v1[32];
        make_v(c0, v0);
        make_v(c1, v1);

        float base0 = (bit0 ? c0[0] : 1.0f - c0[0]) * (bit1 ? c0[1] : 1.0f - c0[1]) * (bit2 ? c0[2] : 1.0f - c0[2]);
        float base1 = (bit0 ? c1[0] : 1.0f - c1[0]) * (bit1 ? c1[1] : 1.0f - c1[1]) * (bit2 ? c1[2] : 1.0f - c1[2]);
        float uA0 = base0 * (1.0f - c0[3]), uB0 = base0 * c0[3];
        float uA1 = base1 * (1.0f - c1[3]), uB1 = base1 * c1[3];

        // ---- dot: 16 b128 LDS reads, each FMA'd for both batches
        const float4* lutp = (const float4*)(&lut[layer][0] + hwl * PPAD);
        const float4* A = lutp + (2 * oct) * 8;
        const float4* B = A + 8;
        float sA0 = 0.f, sA1 = 0.f, sB0 = 0.f, sB1 = 0.f;
        #pragma unroll
        for (int l4 = 0; l4 < 8; ++l4) {
            float4 LA = A[l4];
            float4 LB = B[l4];
            sA0 = fmaf(LA.x, v0[4*l4+0], sA0); sA0 = fmaf(LA.y, v0[4*l4+1], sA0);
            sA0 = fmaf(LA.z, v0[4*l4+2], sA0); sA0 = fmaf(LA.w, v0[4*l4+3], sA0);
            sA1 = fmaf(LA.x, v1[4*l4+0], sA1); sA1 = fmaf(LA.y, v1[4*l4+1], sA1);
            sA1 = fmaf(LA.z, v1[4*l4+2], sA1); sA1 = fmaf(LA.w, v1[4*l4+3], sA1);
            sB0 = fmaf(LB.x, v0[4*l4+0], sB0); sB0 = fmaf(LB.y, v0[4*l4+1], sB0);
            sB0 = fmaf(LB.z, v0[4*l4+2], sB0); sB0 = fmaf(LB.w, v0[4*l4+3], sB0);
            sB1 = fmaf(LB.x, v1[4*l4+0], sB1); sB1 = fmaf(LB.y, v1[4*l4+1], sB1);
            sB1 = fmaf(LB.z, v1[4*l4+2], sB1); sB1 = fmaf(LB.w, v1[4*l4+3], sB1);
        }
        float acc0 = fmaf(uA0, sA0, uB0 * sB0);
        float acc1 = fmaf(uA1, sA1, uB1 * sB1);

        red[bhalf][oct * RPAD + bp * 8 + hwl] = make_float2(acc0, acc1);
        __syncthreads();

        if (th < 64) {
            int hw  = th & 7;
            int bl  = th >> 3;
            int bpi = bl >> 1, par = bl & 1;
            float s = 0.0f;
            #pragma unroll
            for (int o = 0; o < 8; ++o) {
                float2 r = red[bhalf][o * RPAD + bpi * 8 + hw];
                s += par ? r.y : r.x;
            }
            s = fminf(fmaxf(s, 0.0f), 1.0f);
            st_dev(dst + (size_t)(bhalf * 8 + bl) * (HH * WW) + h * 32 + w0 + hw, s);
        }

        if (layer < NLAYERS - 1) neighbor_sync(flags, layer, h, seg);
        src = dst;
    }
}

extern "C" void kernel_launch(void* const* d_in, const int* in_sizes, int n_in,
                              void* d_out, int out_size, void* d_ws, size_t ws_size,
                              hipStream_t stream) {
    const float* x  = (const float*)d_in[0];   // (16,32,32)
    const float* tg = (const float*)d_in[1];   // (4,512,32,32)
    float* out  = (float*)d_out;
    float* bufA = (float*)d_ws;                          // 64 KB
    float* bufB = bufA + 16 * HH * WW;                   // 64 KB
    float* bufC = bufB + 16 * HH * WW;                   // 64 KB
    int*   flags = (int*)((char*)d_ws + 256 * 1024);     // 3*128 slots x 64 B

    // no memset: flags are poison-valued 0xAAAAAAAA; producers store FLAGV(layer)
    asic_fused<<<NBLK, NTHR, 0, stream>>>(x, tg, bufA, bufB, bufC, out, flags);
}